// Round 5
// baseline (201.868 us; speedup 1.0000x reference)
//
#include <hip/hip_runtime.h>

// LSTM forecast: B=1024, S=512, I=1, H=50.
// 1 block = 1 wave = 1 batch. Lane j<50 owns gate rows (i,f,g,o) for hidden
// index j -> lane-local cell update, zero barriers in the 512-step loop.
// R5: pure-f32 matvec (200 v_fma_f32/step, known-native) replacing the fdot2
// path (suspected non-native/emulated on gfx950 -> ~2x VALU bloat seen in
// R4's counters). h broadcast via LDS uniform ds_read_b64 (LDS pipe,
// co-issues with VALU) instead of 25 v_readlane on the VALU pipe.
// Keeps: waves_per_eu(1,1) + asm pins (R4 proved weights stay resident).

#define LOG2E 1.44269504088896340736f
#define B_ 1024
#define S_ 512
#define H_ 50

__device__ __forceinline__ float rcp_(float x) { return __builtin_amdgcn_rcpf(x); }
__device__ __forceinline__ float ex2_(float x) { return __builtin_amdgcn_exp2f(x); }

// Pack W_hh (f32, activation log2-scales folded in) into [gate][k][lane]
// so lane j reads column j coalesced. Also pre-scale W_ih and summed biases.
__global__ void lstm_pack(const float* __restrict__ W_ih, const float* __restrict__ W_hh,
                          const float* __restrict__ b_ih, const float* __restrict__ b_hh,
                          float* __restrict__ wf, float* __restrict__ wih_pk,
                          float* __restrict__ bias_pk)
{
    int tid = blockIdx.x * blockDim.x + threadIdx.x;
    int stride = blockDim.x * gridDim.x;
    for (int p = tid; p < 4 * H_ * 64; p += stride) {
        int j = p & 63;
        int m = (p >> 6) % H_;
        int g = p / (H_ * 64);
        float s = (g == 2) ? (2.0f * LOG2E) : (-LOG2E);
        float a = 0.0f;
        if (j < H_) a = s * W_hh[(g * H_ + j) * H_ + m];
        wf[p] = a;
    }
    for (int p = tid; p < 4 * 64; p += stride) {
        int j = p & 63;
        int g = p >> 6;
        float s = (g == 2) ? (2.0f * LOG2E) : (-LOG2E);
        float wi = 0.0f, bb = 0.0f;
        if (j < H_) {
            int row = g * H_ + j;
            wi = s * W_ih[row];
            bb = s * (b_ih[row] + b_hh[row]);
        }
        wih_pk[p] = wi;
        bias_pk[p] = bb;
    }
}

__global__ __launch_bounds__(64)
__attribute__((amdgpu_waves_per_eu(1, 1)))
void lstm_main(const float* __restrict__ x, const float* __restrict__ h0,
               const float* __restrict__ c0, const float* __restrict__ fc_w,
               const float* __restrict__ fc_b, const float* __restrict__ wf,
               const float* __restrict__ wih_pk, const float* __restrict__ bias_pk,
               float* __restrict__ out)
{
    const int b = blockIdx.x;
    const int j = threadIdx.x;

    __shared__ float hs[64];

    // Per-lane weights: 4 gates x 50 f32 = 200 VGPRs. Coalesced loads; pinned
    // so the compiler can neither remat nor spill them (R3/R4 lessons).
    float w0[H_], w1[H_], w2[H_], w3[H_];
    #pragma unroll
    for (int m = 0; m < H_; ++m) {
        w0[m] = wf[(0 * H_ + m) * 64 + j];
        w1[m] = wf[(1 * H_ + m) * 64 + j];
        w2[m] = wf[(2 * H_ + m) * 64 + j];
        w3[m] = wf[(3 * H_ + m) * 64 + j];
    }
    #pragma unroll
    for (int m = 0; m < H_; ++m) {
        asm volatile("" : "+v"(w0[m]));
        asm volatile("" : "+v"(w1[m]));
        asm volatile("" : "+v"(w2[m]));
        asm volatile("" : "+v"(w3[m]));
    }

    float wih0 = wih_pk[0 * 64 + j], wih1 = wih_pk[1 * 64 + j];
    float wih2 = wih_pk[2 * 64 + j], wih3 = wih_pk[3 * 64 + j];
    float bs0 = bias_pk[0 * 64 + j], bs1 = bias_pk[1 * 64 + j];
    float bs2 = bias_pk[2 * 64 + j], bs3 = bias_pk[3 * 64 + j];
    asm volatile("" : "+v"(wih0), "+v"(wih1), "+v"(wih2), "+v"(wih3),
                      "+v"(bs0), "+v"(bs1), "+v"(bs2), "+v"(bs3));

    float h = (j < H_) ? h0[b * H_ + j] : 0.0f;
    float c = (j < H_) ? c0[b * H_ + j] : 0.0f;
    hs[j] = h;  // single wave: in-order LDS pipe, no barrier needed

    // x row: wave-uniform scalar loads, software-pipelined 1 step ahead.
    const float* __restrict__ xrow = x + b * S_;
    float xt = xrow[0];

    for (int s = 0; s < S_; ++s) {
        int sn = s + 1 < S_ ? s + 1 : S_ - 1;
        float xt_n = xrow[sn];

        // Broadcast h via uniform-address LDS reads (bank-broadcast, no
        // conflicts); 25 ds_read_b64 on the LDS pipe, hidden under the fmas.
        float hp[H_];
        #pragma unroll
        for (int m = 0; m < H_ / 2; ++m) {
            float2 t = *reinterpret_cast<const float2*>(&hs[2 * m]);
            hp[2 * m]     = t.x;
            hp[2 * m + 1] = t.y;
        }

        // 8 independent accumulator chains (4 gates x even/odd) for ILP.
        float a0A = __builtin_fmaf(xt, wih0, bs0), a0B = 0.0f;
        float a1A = __builtin_fmaf(xt, wih1, bs1), a1B = 0.0f;
        float a2A = __builtin_fmaf(xt, wih2, bs2), a2B = 0.0f;
        float a3A = __builtin_fmaf(xt, wih3, bs3), a3B = 0.0f;

        #pragma unroll
        for (int k = 0; k < H_; k += 2) {
            a0A = __builtin_fmaf(hp[k], w0[k], a0A);
            a1A = __builtin_fmaf(hp[k], w1[k], a1A);
            a2A = __builtin_fmaf(hp[k], w2[k], a2A);
            a3A = __builtin_fmaf(hp[k], w3[k], a3A);
            a0B = __builtin_fmaf(hp[k + 1], w0[k + 1], a0B);
            a1B = __builtin_fmaf(hp[k + 1], w1[k + 1], a1B);
            a2B = __builtin_fmaf(hp[k + 1], w2[k + 1], a2B);
            a3B = __builtin_fmaf(hp[k + 1], w3[k + 1], a3B);
        }
        float a0 = a0A + a0B;  // i gate, arg already = -log2e * gate
        float a1 = a1A + a1B;  // f gate
        float a2 = a2A + a2B;  // g gate, arg already = 2*log2e * gate
        float a3 = a3A + a3B;  // o gate

        float ei = ex2_(a0); float si = rcp_(1.0f + ei);          // sigmoid(i)
        float ef = ex2_(a1); float sf = rcp_(1.0f + ef);          // sigmoid(f)
        float eg = ex2_(a2);
        float tg = __builtin_fmaf(-2.0f, rcp_(1.0f + eg), 1.0f);  // tanh(g)
        float eo = ex2_(a3); float so = rcp_(1.0f + eo);          // sigmoid(o)

        c = __builtin_fmaf(sf, c, si * tg);
        float ec = ex2_((2.0f * LOG2E) * c);
        float tc = __builtin_fmaf(-2.0f, rcp_(1.0f + ec), 1.0f);  // tanh(c)
        h = so * tc;

        hs[j] = h;  // publish for next step (in-order LDS, same wave)
        xt = xt_n;
    }

    // outputs: [out (B,1)] [h_n (1,B,H)] [c_n (1,B,H)] concatenated
    if (j < H_) {
        out[B_ + b * H_ + j]            = h;
        out[B_ + B_ * H_ + b * H_ + j]  = c;
    }
    float p = (j < H_) ? h * fc_w[j] : 0.0f;
    #pragma unroll
    for (int off = 32; off > 0; off >>= 1) p += __shfl_xor(p, off);
    if (j == 0) out[b] = p + fc_b[0];
}

extern "C" void kernel_launch(void* const* d_in, const int* in_sizes, int n_in,
                              void* d_out, int out_size, void* d_ws, size_t ws_size,
                              hipStream_t stream)
{
    const float* x    = (const float*)d_in[0];
    const float* h0   = (const float*)d_in[1];
    const float* c0   = (const float*)d_in[2];
    const float* W_ih = (const float*)d_in[3];
    const float* W_hh = (const float*)d_in[4];
    const float* b_ih = (const float*)d_in[5];
    const float* b_hh = (const float*)d_in[6];
    const float* fc_w = (const float*)d_in[7];
    const float* fc_b = (const float*)d_in[8];
    float* out = (float*)d_out;

    float* wf      = (float*)d_ws;                                  // 12800 f32 = 51.2 KB
    float* wih_pk  = (float*)((char*)d_ws + 12800 * 4);             // 256 f32
    float* bias_pk = (float*)((char*)d_ws + 12800 * 4 + 256 * 4);   // 256 f32

    lstm_pack<<<16, 256, 0, stream>>>(W_ih, W_hh, b_ih, b_hh, wf, wih_pk, bias_pk);
    lstm_main<<<B_, 64, 0, stream>>>(x, h0, c0, fc_w, fc_b, wf, wih_pk, bias_pk, out);
}